// Round 1
// baseline (321.434 us; speedup 1.0000x reference)
//
#include <hip/hip_runtime.h>
#include <hip/hip_bf16.h>

// NCE loss: N=4096, E=1024, V=50257, K=25, NORM_TERM=9.0
// loss = -sum_n [ log(p0/(p0+25*pn_t)) + sum_k log(25*pn_k/(pk+25*pn_k)) ] / N
// where p_j = exp(bias[idx]+dot(x[n],W[idx]) - 9).

#define NN 4096
#define EE 1024
#define KK 25

__global__ __launch_bounds__(256) void nce_block_kernel(
    const float* __restrict__ x,
    const int* __restrict__ target,
    const int* __restrict__ noise_idx,
    const float* __restrict__ weight,
    const float* __restrict__ bias,
    const float* __restrict__ noise,
    float* __restrict__ block_loss)
{
    const int n = blockIdx.x;
    __shared__ float xs[EE];
    __shared__ float logits[32];

    // stage x[n] into LDS (256 threads * float4 = 1024 floats)
    const float4* x4 = (const float4*)(x + (size_t)n * EE);
    float4* xs4 = (float4*)xs;
    xs4[threadIdx.x] = x4[threadIdx.x];
    __syncthreads();

    const int wave = threadIdx.x >> 6;
    const int lane = threadIdx.x & 63;

    // each wave handles j = wave, wave+4, ... (26 dots over 4 waves)
    for (int j = wave; j < KK + 1; j += 4) {
        const int row = (j == 0) ? target[n] : noise_idx[n * KK + (j - 1)];
        const float4* w4 = (const float4*)(weight + (size_t)row * EE);
        float acc = 0.0f;
#pragma unroll
        for (int p = 0; p < 4; ++p) {
            float4 xv = xs4[p * 64 + lane];
            float4 wv = w4[p * 64 + lane];
            acc += xv.x * wv.x + xv.y * wv.y + xv.z * wv.z + xv.w * wv.w;
        }
        // wave-level reduction (64 lanes)
#pragma unroll
        for (int off = 32; off > 0; off >>= 1)
            acc += __shfl_down(acc, off);
        if (lane == 0) logits[j] = acc + bias[row];
    }
    __syncthreads();

    if (threadIdx.x == 0) {
        const float kf = (float)KK;
        float p0 = expf(logits[0] - 9.0f);
        float pt = noise[target[n]];
        float loss = logf(p0 / (p0 + kf * pt));
#pragma unroll 5
        for (int j = 1; j <= KK; ++j) {
            float pj = expf(logits[j] - 9.0f);
            float pn25 = kf * noise[noise_idx[n * KK + (j - 1)]];
            loss += logf(pn25 / (pj + pn25));
        }
        block_loss[n] = -loss;
    }
}

__global__ __launch_bounds__(256) void nce_reduce_kernel(
    const float* __restrict__ block_loss, float* __restrict__ out)
{
    float acc = 0.0f;
    for (int i = threadIdx.x; i < NN; i += 256)
        acc += block_loss[i];
#pragma unroll
    for (int off = 32; off > 0; off >>= 1)
        acc += __shfl_down(acc, off);
    __shared__ float s[4];
    const int wave = threadIdx.x >> 6;
    const int lane = threadIdx.x & 63;
    if (lane == 0) s[wave] = acc;
    __syncthreads();
    if (threadIdx.x == 0)
        out[0] = (s[0] + s[1] + s[2] + s[3]) / (float)NN;
}

extern "C" void kernel_launch(void* const* d_in, const int* in_sizes, int n_in,
                              void* d_out, int out_size, void* d_ws, size_t ws_size,
                              hipStream_t stream) {
    const float* x        = (const float*)d_in[0];
    const int*   target   = (const int*)d_in[1];
    const int*   noiseIdx = (const int*)d_in[2];
    const float* weight   = (const float*)d_in[3];
    const float* bias     = (const float*)d_in[4];
    const float* noise    = (const float*)d_in[5];
    float* out = (float*)d_out;
    float* block_loss = (float*)d_ws;  // NN floats

    nce_block_kernel<<<NN, 256, 0, stream>>>(x, target, noiseIdx, weight, bias, noise, block_loss);
    nce_reduce_kernel<<<1, 256, 0, stream>>>(block_loss, out);
}

// Round 2
// 315.396 us; speedup vs baseline: 1.0191x; 1.0191x over previous
//
#include <hip/hip_runtime.h>
#include <hip/hip_bf16.h>

// NCE loss: N=4096, E=1024, V=50257, K=25, NORM_TERM=9.0
// loss = -sum_n [ log(p0/(p0+25*pn_t)) + sum_k log(25*pn_k/(pk+25*pn_k)) ] / N
// where p_j = exp(bias[idx] + dot(x[n], W[idx]) - 9).
//
// Structure: one 256-thread block per sample n. x[n] (1024 f32) lives in
// registers (4 float4/lane). Wave w handles rows j = w, w+4, ... (7 rows for
// waves 0-1, 6 for waves 2-3; all control wave-uniform -> no divergence).
// Fully unrolled row loop => up to 28 global_load_dwordx4 in flight per wave.
// 7 independent butterfly-reduce chains, per-wave epilogue, one LDS combine.

#define NN 4096
#define EE 1024
#define KK 25

__device__ __forceinline__ void fma4(float4& a, const float4& p, const float4& q) {
    a.x += p.x * q.x; a.y += p.y * q.y; a.z += p.z * q.z; a.w += p.w * q.w;
}

__global__ __launch_bounds__(256) void nce_main_kernel(
    const float* __restrict__ x,
    const int* __restrict__ target,
    const int* __restrict__ noise_idx,
    const float* __restrict__ weight,
    const float* __restrict__ bias,
    const float* __restrict__ noise,
    float* __restrict__ block_loss)
{
    const int n = blockIdx.x;
    const int wave = threadIdx.x >> 6;
    const int lane = threadIdx.x & 63;

    // x[n] into registers: float4 indices {lane, 64+lane, 128+lane, 192+lane}
    const float4* x4 = (const float4*)(x + (size_t)n * EE);
    const float4 xr0 = x4[lane];
    const float4 xr1 = x4[64 + lane];
    const float4 xr2 = x4[128 + lane];
    const float4 xr3 = x4[192 + lane];

    // waves 0,1 -> 7 rows; waves 2,3 -> 6 rows (j = wave + 4*jj < 26)
    const int nj = (wave < 2) ? 7 : 6;

    float sacc[7];
    int rows[7];

#pragma unroll
    for (int jj = 0; jj < 7; ++jj) {
        const int j = wave + (jj << 2);
        const bool valid = (jj < nj);  // wave-uniform
        int row = 0;
        float4 a = make_float4(0.f, 0.f, 0.f, 0.f);
        if (valid) {
            row = (j == 0) ? target[n] : noise_idx[n * KK + (j - 1)];
            const float4* w4 = (const float4*)(weight + (size_t)row * EE);
            const float4 w0 = w4[lane];
            const float4 w1 = w4[64 + lane];
            const float4 w2 = w4[128 + lane];
            const float4 w3 = w4[192 + lane];
            fma4(a, xr0, w0);
            fma4(a, xr1, w1);
            fma4(a, xr2, w2);
            fma4(a, xr3, w3);
        }
        rows[jj] = row;
        sacc[jj] = (a.x + a.y) + (a.z + a.w);
    }

    // 7 independent butterfly reductions (interleaved by the compiler)
#pragma unroll
    for (int jj = 0; jj < 7; ++jj) {
#pragma unroll
        for (int off = 32; off > 0; off >>= 1)
            sacc[jj] += __shfl_xor(sacc[jj], off);
    }

    __shared__ float swave[4];
    if (lane == 0) {
        float part = 0.0f;
#pragma unroll
        for (int jj = 0; jj < 7; ++jj) {
            if (jj < nj) {
                const int j = wave + (jj << 2);
                const int row = rows[jj];
                const float logit = sacc[jj] + bias[row];
                const float p = expf(logit - 9.0f);
                const float pn25 = 25.0f * noise[row];
                part += (j == 0) ? logf(p / (p + pn25))
                                 : logf(pn25 / (p + pn25));
            }
        }
        swave[wave] = part;
    }
    __syncthreads();
    if (threadIdx.x == 0)
        block_loss[n] = -((swave[0] + swave[1]) + (swave[2] + swave[3]));
}

__global__ __launch_bounds__(256) void nce_reduce_kernel(
    const float* __restrict__ block_loss, float* __restrict__ out)
{
    float acc = 0.0f;
    for (int i = threadIdx.x; i < NN; i += 256)
        acc += block_loss[i];
#pragma unroll
    for (int off = 32; off > 0; off >>= 1)
        acc += __shfl_down(acc, off);
    __shared__ float s[4];
    const int wave = threadIdx.x >> 6;
    const int lane = threadIdx.x & 63;
    if (lane == 0) s[wave] = acc;
    __syncthreads();
    if (threadIdx.x == 0)
        out[0] = ((s[0] + s[1]) + (s[2] + s[3])) / (float)NN;
}

extern "C" void kernel_launch(void* const* d_in, const int* in_sizes, int n_in,
                              void* d_out, int out_size, void* d_ws, size_t ws_size,
                              hipStream_t stream) {
    const float* x        = (const float*)d_in[0];
    const int*   target   = (const int*)d_in[1];
    const int*   noiseIdx = (const int*)d_in[2];
    const float* weight   = (const float*)d_in[3];
    const float* bias     = (const float*)d_in[4];
    const float* noise    = (const float*)d_in[5];
    float* out = (float*)d_out;
    float* block_loss = (float*)d_ws;  // NN floats

    nce_main_kernel<<<NN, 256, 0, stream>>>(x, target, noiseIdx, weight, bias, noise, block_loss);
    nce_reduce_kernel<<<1, 256, 0, stream>>>(block_loss, out);
}

// Round 3
// 315.394 us; speedup vs baseline: 1.0192x; 1.0000x over previous
//
#include <hip/hip_runtime.h>
#include <hip/hip_bf16.h>

// NCE loss: N=4096, E=1024, V=50257, K=25, NORM_TERM=9.0
// loss = -sum_n [ log(p0/(p0+25*pn_t)) + sum_k log(25*pn_k/(pk+25*pn_k)) ] / N
// p_j = exp(bias[idx] + dot(x[n], W[idx]) - 9).
//
// Loss is separable per (n,j) term. One 256-thread block per sample; wave w
// handles rows j = w, w+4, ... (7/7/6/6). Two-phase: issue ALL loads (7 index
// + 4 x dwordx4 + 28 weight dwordx4 per wave) before any FMA -> max vmcnt
// overlap. Per-wave partial -> atomicAdd into 256 spread buckets in d_ws
// (64 adds/bucket, no contention). Finalize kernel sums 256 buckets.

#define NN 4096
#define EE 1024
#define KK 25
#define NBUCKET 256

__device__ __forceinline__ void fma4(float4& a, const float4& p, const float4& q) {
    a.x += p.x * q.x; a.y += p.y * q.y; a.z += p.z * q.z; a.w += p.w * q.w;
}

__global__ __launch_bounds__(256) void nce_main_kernel(
    const float* __restrict__ x,
    const int* __restrict__ target,
    const int* __restrict__ noise_idx,
    const float* __restrict__ weight,
    const float* __restrict__ bias,
    const float* __restrict__ noise,
    float* __restrict__ buckets)
{
    const int n = blockIdx.x;
    const int wave = threadIdx.x >> 6;
    const int lane = threadIdx.x & 63;

    // waves 0,1 -> 7 rows; waves 2,3 -> 6 rows (j = wave + 4*jj < 26)
    const int nj = (wave < 2) ? 7 : 6;

    // ---- phase 0: indices (wave-uniform scalar loads) ----
    int rows[7];
#pragma unroll
    for (int jj = 0; jj < 7; ++jj) {
        const int j = wave + (jj << 2);
        rows[jj] = (jj < nj) ? ((j == 0) ? target[n] : noise_idx[n * KK + (j - 1)])
                             : 0;
    }

    // ---- phase 1: issue ALL vector loads ----
    const float4* x4 = (const float4*)(x + (size_t)n * EE);
    float4 xr[4];
#pragma unroll
    for (int p = 0; p < 4; ++p) xr[p] = x4[p * 64 + lane];

    float4 wr[7][4];
#pragma unroll
    for (int jj = 0; jj < 7; ++jj) {
        const float4* w4 = (const float4*)(weight + (size_t)rows[jj] * EE);
#pragma unroll
        for (int p = 0; p < 4; ++p) wr[jj][p] = w4[p * 64 + lane];
    }

    // ---- phase 2: FMAs ----
    float sacc[7];
#pragma unroll
    for (int jj = 0; jj < 7; ++jj) {
        float4 a = make_float4(0.f, 0.f, 0.f, 0.f);
#pragma unroll
        for (int p = 0; p < 4; ++p) fma4(a, xr[p], wr[jj][p]);
        sacc[jj] = (a.x + a.y) + (a.z + a.w);
    }

    // ---- phase 3: 7 independent butterfly reductions ----
#pragma unroll
    for (int jj = 0; jj < 7; ++jj) {
#pragma unroll
        for (int off = 32; off > 0; off >>= 1)
            sacc[jj] += __shfl_xor(sacc[jj], off);
    }

    // ---- phase 4: per-wave epilogue, bucket atomicAdd ----
    if (lane == 0) {
        float part = 0.0f;
#pragma unroll
        for (int jj = 0; jj < 7; ++jj) {
            if (jj < nj) {
                const int j = wave + (jj << 2);
                const int row = rows[jj];
                const float logit = sacc[jj] + bias[row];
                const float p = expf(logit - 9.0f);
                const float pn25 = 25.0f * noise[row];
                part += (j == 0) ? logf(p / (p + pn25))
                                 : logf(pn25 / (p + pn25));
            }
        }
        atomicAdd(&buckets[(n + wave * 64) & (NBUCKET - 1)], -part);
    }
}

__global__ __launch_bounds__(64) void nce_finalize_kernel(
    const float* __restrict__ buckets, float* __restrict__ out)
{
    float acc = buckets[threadIdx.x] + buckets[threadIdx.x + 64]
              + buckets[threadIdx.x + 128] + buckets[threadIdx.x + 192];
#pragma unroll
    for (int off = 32; off > 0; off >>= 1)
        acc += __shfl_xor(acc, off);
    if (threadIdx.x == 0)
        out[0] = acc / (float)NN;
}

extern "C" void kernel_launch(void* const* d_in, const int* in_sizes, int n_in,
                              void* d_out, int out_size, void* d_ws, size_t ws_size,
                              hipStream_t stream) {
    const float* x        = (const float*)d_in[0];
    const int*   target   = (const int*)d_in[1];
    const int*   noiseIdx = (const int*)d_in[2];
    const float* weight   = (const float*)d_in[3];
    const float* bias     = (const float*)d_in[4];
    const float* noise    = (const float*)d_in[5];
    float* out = (float*)d_out;
    float* buckets = (float*)d_ws;  // NBUCKET floats

    hipMemsetAsync(buckets, 0, NBUCKET * sizeof(float), stream);
    nce_main_kernel<<<NN, 256, 0, stream>>>(x, target, noiseIdx, weight, bias, noise, buckets);
    nce_finalize_kernel<<<1, 64, 0, stream>>>(buckets, out);
}